// Round 10
// baseline (464.428 us; speedup 1.0000x reference)
//
#include <hip/hip_runtime.h>
#include <stdint.h>

// ---------- types ----------
typedef __attribute__((ext_vector_type(8))) short   short8;
typedef __attribute__((ext_vector_type(8))) __bf16  bf16x8;
typedef __attribute__((ext_vector_type(4))) float   floatx4;

#define DEV static __device__ __forceinline__

// f32 -> bf16 (RNE) raw bits
DEV unsigned short f2b(float f) {
  union { float f; unsigned u; } v; v.f = f;
  unsigned u = v.u;
  unsigned r = u + 0x7FFFu + ((u >> 16) & 1u);
  return (unsigned short)(r >> 16);
}

// async global->LDS, 16 bytes per lane. LDS dest must be wave-uniform base + lane*16.
DEV void gload_lds16(const void* g, void* l) {
  __builtin_amdgcn_global_load_lds(
      (const __attribute__((address_space(1))) unsigned int*)g,
      (__attribute__((address_space(3))) unsigned int*)l,
      16, 0, 0);
}

// ---------- weights f32->bf16 convert + sums zero-init ----------
__global__ void cvtw_kernel(const float* __restrict__ a, unsigned short* __restrict__ oa, int na4,
                            const float* __restrict__ b, unsigned short* __restrict__ ob, int nb4,
                            float* __restrict__ zp, int nz) {
  int i = blockIdx.x * blockDim.x + threadIdx.x;
  if (i < na4) {
    float4 v = ((const float4*)a)[i];
    ushort4 o; o.x = f2b(v.x); o.y = f2b(v.y); o.z = f2b(v.z); o.w = f2b(v.w);
    ((ushort4*)oa)[i] = o;
  } else if (i < na4 + nb4) {
    int k = i - na4;
    float4 v = ((const float4*)b)[k];
    ushort4 o; o.x = f2b(v.x); o.y = f2b(v.y); o.z = f2b(v.z); o.w = f2b(v.w);
    ((ushort4*)ob)[k] = o;
  } else if (i < na4 + nb4 + nz) {
    zp[i - na4 - nb4] = 0.f;
  }
}

// ---------- projection GEMM (R2/R7-verified, unchanged): C[M][256] = A[M][K]*Bt[256][K]^T ----------
// Used for BOTH Q (grid 128, K=768) and K (grid 512, K=1280) projections.
// No HT emission anywhere anymore -> WRITE drops to the bf16 C only.
template <int WRITE_HT>
__global__ __launch_bounds__(256) void proj_gemm(
    const float* __restrict__ A32, const unsigned short* __restrict__ Bt,
    unsigned short* __restrict__ C, unsigned short* __restrict__ HT,
    int K, int lda) {
  __shared__ float          Af32[2][64 * 32];              // 16 KB (dbuf, raw f32 A)
  __shared__ unsigned short Bs[2][256 * 32];               // 32 KB (dbuf)
  __shared__ unsigned short As[64 * 32];                   // 4 KB  (bf16 A)

  const int m0   = blockIdx.x * 64;
  const int t    = threadIdx.x;
  const int lane = t & 63;
  const int wave = t >> 6;            // 0..3
  const int wn   = wave * 64;
  const int r16  = lane & 15;
  const int q    = lane >> 4;
  const int nt   = K >> 5;

  floatx4 acc[4][4];
#pragma unroll
  for (int i = 0; i < 4; ++i)
#pragma unroll
    for (int j = 0; j < 4; ++j) acc[i][j] = (floatx4){0.f, 0.f, 0.f, 0.f};

  // stage(it) -> buf: A (2 chunks) then B (4 chunks); 6 vmem ops, program order.
  auto stage = [&](int it, int buf) {
    const int kt = it << 5;
#pragma unroll
    for (int cc = 0; cc < 2; ++cc) {
      int c = t + cc * 256;
      gload_lds16(A32 + (size_t)(m0 + (c >> 3)) * lda + kt + (c & 7) * 4,
                  &Af32[buf][c * 4]);
    }
#pragma unroll
    for (int cc = 0; cc < 4; ++cc) {
      int c = t + cc * 256;
      gload_lds16(Bt + (size_t)(c >> 2) * K + kt + (c & 3) * 8, &Bs[buf][c * 8]);
    }
  };

  stage(0, 0);
  stage(1, 1);

  for (int it = 0; it < nt; ++it) {
    const int cur = it & 1;

    if (it == nt - 1) { asm volatile("s_waitcnt vmcnt(0)" ::: "memory"); }
    else              { asm volatile("s_waitcnt vmcnt(6)" ::: "memory"); }
    __builtin_amdgcn_sched_barrier(0);

    // convert Af32[cur] -> As bf16 (each thread reads the chunks it staged itself)
    {
      const int row = t >> 3;
      const int kc  = t & 7;
      float4 v0 = *(const float4*)&Af32[cur][t * 4];
      float4 v1 = *(const float4*)&Af32[cur][t * 4 + 1024];
      ushort4 p0, p1;
      p0.x = f2b(v0.x); p0.y = f2b(v0.y); p0.z = f2b(v0.z); p0.w = f2b(v0.w);
      p1.x = f2b(v1.x); p1.y = f2b(v1.y); p1.z = f2b(v1.z); p1.w = f2b(v1.w);
      *(ushort4*)&As[row * 32 + kc * 4]        = p0;
      *(ushort4*)&As[(row + 32) * 32 + kc * 4] = p1;
    }
    asm volatile("s_waitcnt lgkmcnt(0)\n\ts_barrier" ::: "memory");  // barrier A
    __builtin_amdgcn_sched_barrier(0);

    bf16x8 af[4], bfr[4];
#pragma unroll
    for (int i = 0; i < 4; ++i) af[i]  = *(const bf16x8*)&As[(i * 16 + r16) * 32 + q * 8];
#pragma unroll
    for (int j = 0; j < 4; ++j) bfr[j] = *(const bf16x8*)&Bs[cur][(wn + j * 16 + r16) * 32 + q * 8];
    asm volatile("s_waitcnt lgkmcnt(0)\n\ts_barrier" ::: "memory");  // barrier B
    __builtin_amdgcn_sched_barrier(0);

    if (it + 2 < nt) stage(it + 2, cur);

#pragma unroll
    for (int i = 0; i < 4; ++i)
#pragma unroll
      for (int j = 0; j < 4; ++j)
        acc[i][j] = __builtin_amdgcn_mfma_f32_16x16x32_bf16(af[i], bfr[j], acc[i][j], 0, 0, 0);
  }

#pragma unroll
  for (int i = 0; i < 4; ++i) {
#pragma unroll
    for (int r = 0; r < 4; ++r) {
      int m = m0 + i * 16 + q * 4 + r;
#pragma unroll
      for (int j = 0; j < 4; ++j) {
        int n = wn + j * 16 + r16;
        C[(size_t)m * 256 + n] = f2b(acc[i][j][r]);
      }
    }
  }
}

// ---------- NT GEMM for E = exp(QK^T) (R7-verified, unchanged), 128x128, XCD swizzle ----------
// Single-__syncthreads-per-iteration double-buffer.
// EPI 1: C=bf16 exp(v*escale), atomicAdd row sums.
template <int EPI>
__global__ void gemm_nt(const unsigned short* __restrict__ Ab, const unsigned short* __restrict__ Btb,
                        void* __restrict__ Cpv, float* __restrict__ sums,
                        int K, int lda, int ldb, int ldc,
                        long long sA, long long sB, long long sC, int sstride,
                        float escale, int nx, int tiles_pb) {
  __shared__ unsigned short As[2][128 * 32];   // 16 KB (dbuf)
  __shared__ unsigned short Bs[2][128 * 32];   // 16 KB (dbuf)

  const int g   = blockIdx.x;
  const int xcd = g & 7;
  const int jj  = g >> 3;
  const int bz  = xcd * 2 + jj / tiles_pb;
  const int tt  = jj % tiles_pb;
  const int m0  = (tt / nx) * 128;
  const int n0  = (tt % nx) * 128;

  const int t    = threadIdx.x;
  const int lane = t & 63;
  const int wave = t >> 6;
  const int wm   = (wave & 1) * 64;
  const int wn   = (wave >> 1) * 64;
  const int r16  = lane & 15;
  const int q    = lane >> 4;
  const int nt   = K >> 5;

  const unsigned short* Bt = Btb + (long long)bz * sB;
  const unsigned short* A  = Ab + (long long)bz * sA;

  floatx4 acc[4][4];
#pragma unroll
  for (int i = 0; i < 4; ++i)
#pragma unroll
    for (int j = 0; j < 4; ++j) acc[i][j] = (floatx4){0.f, 0.f, 0.f, 0.f};

  auto stage = [&](int it, int buf) {
    const int kt = it << 5;
#pragma unroll
    for (int cc = 0; cc < 2; ++cc) {
      int c = t + cc * 256;
      gload_lds16(Bt + (size_t)(n0 + (c >> 2)) * ldb + kt + (c & 3) * 8, &Bs[buf][c * 8]);
    }
#pragma unroll
    for (int cc = 0; cc < 2; ++cc) {
      int c = t + cc * 256;
      gload_lds16(A + (size_t)(m0 + (c >> 2)) * lda + kt + (c & 3) * 8, &As[buf][c * 8]);
    }
  };

  stage(0, 0);
  __syncthreads();

  for (int it = 0; it < nt; ++it) {
    const int cur = it & 1;

    if (it + 1 < nt) stage(it + 1, cur ^ 1);

    bf16x8 af[4], bfr[4];
#pragma unroll
    for (int i = 0; i < 4; ++i) af[i]  = *(const bf16x8*)&As[cur][(wm + i * 16 + r16) * 32 + q * 8];
#pragma unroll
    for (int j = 0; j < 4; ++j) bfr[j] = *(const bf16x8*)&Bs[cur][(wn + j * 16 + r16) * 32 + q * 8];
#pragma unroll
    for (int i = 0; i < 4; ++i)
#pragma unroll
      for (int j = 0; j < 4; ++j)
        acc[i][j] = __builtin_amdgcn_mfma_f32_16x16x32_bf16(af[i], bfr[j], acc[i][j], 0, 0, 0);

    __syncthreads();
  }

  if constexpr (EPI == 1) {
    unsigned short* C = (unsigned short*)Cpv + (long long)bz * sC;
#pragma unroll
    for (int i = 0; i < 4; ++i) {
#pragma unroll
      for (int r = 0; r < 4; ++r) {
        int m = m0 + wm + i * 16 + q * 4 + r;
        float ps = 0.f;
#pragma unroll
        for (int j = 0; j < 4; ++j) {
          int n = n0 + wn + j * 16 + r16;
          float v = __expf(acc[i][j][r] * escale);
          ps += v;
          C[(size_t)m * ldc + n] = f2b(v);
        }
#pragma unroll
        for (int msk = 1; msk < 16; msk <<= 1) ps += __shfl_xor(ps, msk, 64);
        if (r16 == 0) atomicAdd(&sums[(long long)bz * sstride + m], ps);
      }
    }
  }
}

// ---------- NN GEMM for Z = diag(1/sums) * E * H : reads H (f32) directly ----------
// Replaces the HT-based nt2: no HT materialization anywhere.
// B-tile [32 k][128 n] from H rows kt..kt+32 (cols n0..n0+128, f32), staged via
// registers -> f2b -> TRANSPOSED LDS write into Bsn[n][PITCH=40] (identical
// [n][k] semantics to the NT kernel's Bs; pitch 80 B keeps b128 frags 16B-aligned,
// banks <=2-way). T14 split: global loads issued BEFORE the MFMA phase, cvt +
// ds_writes AFTER (H latency hides under compute). Single-sync dbuf structure
// byte-parallel to the R7-verified gemm_nt. Math identical to old path (HT was
// f2b(H); f2b now applied in-kernel) -> absmax unchanged.
__global__ void gemm_nn(const unsigned short* __restrict__ Ab, const float* __restrict__ Hb,
                        float* __restrict__ Cp, const float* __restrict__ sums,
                        int K, int lda, int ldb, int ldc,
                        long long sA, long long sB, long long sC, int sstride,
                        int nx, int tiles_pb) {
  constexpr int BP = 40;                        // Bsn pitch in shorts (80 B)
  __shared__ unsigned short As[2][128 * 32];    // 16 KB (dbuf, E bf16)
  __shared__ unsigned short Bsn[2][128 * BP];   // 20 KB (dbuf, H bf16 transposed)

  const int g   = blockIdx.x;
  const int xcd = g & 7;
  const int jj  = g >> 3;
  const int bz  = xcd * 2 + jj / tiles_pb;
  const int tt  = jj % tiles_pb;
  const int m0  = (tt / nx) * 128;
  const int n0  = (tt % nx) * 128;

  const int t    = threadIdx.x;
  const int lane = t & 63;
  const int wave = t >> 6;
  const int wm   = (wave & 1) * 64;
  const int wn   = (wave >> 1) * 64;
  const int r16  = lane & 15;
  const int q    = lane >> 4;
  const int nt   = K >> 5;                      // 64

  const unsigned short* A = Ab + (long long)bz * sA;
  const float*          H = Hb + (long long)bz * sB;

  // B-stage mapping: thread t covers k-row kr = t>>3 (0..31), cols nc0..nc0+16.
  const int kr  = t >> 3;
  const int nc0 = (t & 7) * 16;

  floatx4 acc[4][4];
#pragma unroll
  for (int i = 0; i < 4; ++i)
#pragma unroll
    for (int j = 0; j < 4; ++j) acc[i][j] = (floatx4){0.f, 0.f, 0.f, 0.f};

  // A-stage: 2 gload_lds chunks (as in gemm_nt)
  auto stageA = [&](int it, int buf) {
    const int kt = it << 5;
#pragma unroll
    for (int cc = 0; cc < 2; ++cc) {
      int c = t + cc * 256;
      gload_lds16(A + (size_t)(m0 + (c >> 2)) * lda + kt + (c & 3) * 8, &As[buf][c * 8]);
    }
  };
  // B-load: 4 float4 (16 f32 of one H row slice) into registers
  auto loadB = [&](int it, float4 (&h)[4]) {
    const float* hp = H + (size_t)((it << 5) + kr) * ldb + n0 + nc0;
    h[0] = ((const float4*)hp)[0];
    h[1] = ((const float4*)hp)[1];
    h[2] = ((const float4*)hp)[2];
    h[3] = ((const float4*)hp)[3];
  };
  // B-write: f2b + transposed scatter Bsn[n][kr]
  auto writeB = [&](int buf, const float4 (&h)[4]) {
    unsigned short* bp = &Bsn[buf][0];
#pragma unroll
    for (int v4 = 0; v4 < 4; ++v4) {
      bp[(nc0 + v4 * 4 + 0) * BP + kr] = f2b(h[v4].x);
      bp[(nc0 + v4 * 4 + 1) * BP + kr] = f2b(h[v4].y);
      bp[(nc0 + v4 * 4 + 2) * BP + kr] = f2b(h[v4].z);
      bp[(nc0 + v4 * 4 + 3) * BP + kr] = f2b(h[v4].w);
    }
  };

  // prologue: stage(0) fully
  {
    float4 h[4];
    stageA(0, 0);
    loadB(0, h);
    writeB(0, h);
  }
  __syncthreads();

  for (int it = 0; it < nt; ++it) {
    const int cur = it & 1;

    float4 h[4];
    if (it + 1 < nt) {                 // issue-early: A gload_lds + B reg loads
      stageA(it + 1, cur ^ 1);
      loadB(it + 1, h);
    }

    bf16x8 af[4], bfr[4];
#pragma unroll
    for (int i = 0; i < 4; ++i) af[i]  = *(const bf16x8*)&As[cur][(wm + i * 16 + r16) * 32 + q * 8];
#pragma unroll
    for (int j = 0; j < 4; ++j) bfr[j] = *(const bf16x8*)&Bsn[cur][(wn + j * 16 + r16) * BP + q * 8];
#pragma unroll
    for (int i = 0; i < 4; ++i)
#pragma unroll
      for (int j = 0; j < 4; ++j)
        acc[i][j] = __builtin_amdgcn_mfma_f32_16x16x32_bf16(af[i], bfr[j], acc[i][j], 0, 0, 0);

    if (it + 1 < nt) writeB(cur ^ 1, h);   // write-late (H latency hidden under MFMA)

    __syncthreads();                   // drains gload_lds + ds_writes; protects reuse
  }

  // epilogue: Z = acc / sums[row], f32
  float* C = Cp + (long long)bz * sC;
  const float* sb = sums + (long long)bz * sstride;
#pragma unroll
  for (int i = 0; i < 4; ++i) {
#pragma unroll
    for (int r = 0; r < 4; ++r) {
      int m = m0 + wm + i * 16 + q * 4 + r;
      float sc = 1.0f / sb[m];
#pragma unroll
      for (int j = 0; j < 4; ++j) {
        int n = n0 + wn + j * 16 + r16;
        C[(size_t)m * ldc + n] = acc[i][j][r] * sc;
      }
    }
  }
}

// ---------- launch ----------
extern "C" void kernel_launch(void* const* d_in, const int* in_sizes, int n_in,
                              void* d_out, int out_size, void* d_ws, size_t ws_size,
                              hipStream_t stream) {
  (void)in_sizes; (void)n_in; (void)out_size; (void)ws_size;
  const float* H  = (const float*)d_in[0];   // [16][2048][1280]
  const float* G  = (const float*)d_in[1];   // [16][512][768]
  const float* Wq = (const float*)d_in[2];   // [256][768]
  const float* Wk = (const float*)d_in[3];   // [256][1280]
  float* Z = (float*)d_out;                  // [16][512][1280]

  constexpr int B = 16, L = 2048, Dh = 1280, T = 512, Dg = 768, P = 256;

  char* ws = (char*)d_ws;
  size_t off = 0;
  auto alloc = [&](size_t bytes) { void* p = ws + off; off += (bytes + 255) & ~(size_t)255; return p; };
  unsigned short* Wqbf = (unsigned short*)alloc((size_t)P * Dg * 2);
  unsigned short* Wkbf = (unsigned short*)alloc((size_t)P * Dh * 2);
  unsigned short* Qbf  = (unsigned short*)alloc((size_t)B * T * P * 2);    // 4 MB
  unsigned short* Kbf  = (unsigned short*)alloc((size_t)B * L * P * 2);    // 16 MB
  unsigned short* E    = (unsigned short*)alloc((size_t)B * T * L * 2);    // 32 MB
  float*          sums = (float*)alloc((size_t)B * T * 4);
  // total ~52 MB of ws (HT eliminated: -80 MB)

  // weights convert + sums zero-init (one small kernel)
  {
    int na4 = P * Dg / 4, nb4 = P * Dh / 4, nz = B * T;
    cvtw_kernel<<<(na4 + nb4 + nz + 255) / 256, 256, 0, stream>>>(
        Wq, Wqbf, na4, Wk, Wkbf, nb4, sums, nz);
  }

  // Q = G(f32) * Wqbf^T : [8192][256]
  proj_gemm<0><<<B * T / 64, 256, 0, stream>>>(G, Wqbf, Qbf, nullptr, Dg, Dg);
  // K = H(f32) * Wkbf^T : [32768][256] — pure projection, no HT emission
  proj_gemm<0><<<B * L / 64, 256, 0, stream>>>(H, Wkbf, Kbf, nullptr, Dh, Dh);

  // E = exp(scale * Qb * Kb^T) + row sums : per b [512][2048], 64 tiles/batch
  gemm_nt<1><<<B * (T / 128) * (L / 128), 256, 0, stream>>>(
      Qbf, Kbf, E, sums, P, P, P, L,
      (long long)T * P, (long long)L * P, (long long)T * L, T,
      0.0625f, L / 128, (T / 128) * (L / 128));

  // Z = diag(1/sums) * Eb * Hb : per b [512][1280] f32, 40 tiles/batch (NN, H direct)
  gemm_nn<<<B * (T / 128) * (Dh / 128), 256, 0, stream>>>(
      E, H, Z, sums, L, L, Dh, Dh,
      (long long)T * L, (long long)L * Dh, (long long)T * Dh, T,
      Dh / 128, (T / 128) * (Dh / 128));
}

// Round 11
// 409.104 us; speedup vs baseline: 1.1352x; 1.1352x over previous
//
#include <hip/hip_runtime.h>
#include <stdint.h>

// ---------- types ----------
typedef __attribute__((ext_vector_type(8))) short   short8;
typedef __attribute__((ext_vector_type(8))) __bf16  bf16x8;
typedef __attribute__((ext_vector_type(4))) float   floatx4;

#define DEV static __device__ __forceinline__

// f32 -> bf16 (RNE) raw bits
DEV unsigned short f2b(float f) {
  union { float f; unsigned u; } v; v.f = f;
  unsigned u = v.u;
  unsigned r = u + 0x7FFFu + ((u >> 16) & 1u);
  return (unsigned short)(r >> 16);
}

// async global->LDS, 16 bytes per lane. LDS dest must be wave-uniform base + lane*16.
DEV void gload_lds16(const void* g, void* l) {
  __builtin_amdgcn_global_load_lds(
      (const __attribute__((address_space(1))) unsigned int*)g,
      (__attribute__((address_space(3))) unsigned int*)l,
      16, 0, 0);
}

// ---------- weights f32->bf16 convert + sums zero-init ----------
__global__ void cvtw_kernel(const float* __restrict__ a, unsigned short* __restrict__ oa, int na4,
                            const float* __restrict__ b, unsigned short* __restrict__ ob, int nb4,
                            float* __restrict__ zp, int nz) {
  int i = blockIdx.x * blockDim.x + threadIdx.x;
  if (i < na4) {
    float4 v = ((const float4*)a)[i];
    ushort4 o; o.x = f2b(v.x); o.y = f2b(v.y); o.z = f2b(v.z); o.w = f2b(v.w);
    ((ushort4*)oa)[i] = o;
  } else if (i < na4 + nb4) {
    int k = i - na4;
    float4 v = ((const float4*)b)[k];
    ushort4 o; o.x = f2b(v.x); o.y = f2b(v.y); o.z = f2b(v.z); o.w = f2b(v.w);
    ((ushort4*)ob)[k] = o;
  } else if (i < na4 + nb4 + nz) {
    zp[i - na4 - nb4] = 0.f;
  }
}

// ---------- Q projection GEMM (R2/R7-verified, unchanged): C[M][256] = A[M][K]*Bt[256][K]^T ----------
template <int WRITE_HT>
__global__ __launch_bounds__(256) void proj_gemm(
    const float* __restrict__ A32, const unsigned short* __restrict__ Bt,
    unsigned short* __restrict__ C, unsigned short* __restrict__ HT,
    int K, int lda) {
  __shared__ float          Af32[2][64 * 32];              // 16 KB (dbuf, raw f32 A)
  __shared__ unsigned short Bs[2][256 * 32];               // 32 KB (dbuf)
  __shared__ unsigned short As[64 * 32];                   // 4 KB  (bf16 A)

  const int m0   = blockIdx.x * 64;
  const int t    = threadIdx.x;
  const int lane = t & 63;
  const int wave = t >> 6;            // 0..3
  const int wn   = wave * 64;
  const int r16  = lane & 15;
  const int q    = lane >> 4;
  const int nt   = K >> 5;

  floatx4 acc[4][4];
#pragma unroll
  for (int i = 0; i < 4; ++i)
#pragma unroll
    for (int j = 0; j < 4; ++j) acc[i][j] = (floatx4){0.f, 0.f, 0.f, 0.f};

  // stage(it) -> buf: A (2 chunks) then B (4 chunks); 6 vmem ops, program order.
  auto stage = [&](int it, int buf) {
    const int kt = it << 5;
#pragma unroll
    for (int cc = 0; cc < 2; ++cc) {
      int c = t + cc * 256;
      gload_lds16(A32 + (size_t)(m0 + (c >> 3)) * lda + kt + (c & 7) * 4,
                  &Af32[buf][c * 4]);
    }
#pragma unroll
    for (int cc = 0; cc < 4; ++cc) {
      int c = t + cc * 256;
      gload_lds16(Bt + (size_t)(c >> 2) * K + kt + (c & 3) * 8, &Bs[buf][c * 8]);
    }
  };

  stage(0, 0);
  stage(1, 1);

  for (int it = 0; it < nt; ++it) {
    const int cur = it & 1;

    if (it == nt - 1) { asm volatile("s_waitcnt vmcnt(0)" ::: "memory"); }
    else              { asm volatile("s_waitcnt vmcnt(6)" ::: "memory"); }
    __builtin_amdgcn_sched_barrier(0);

    // convert Af32[cur] -> As bf16 (each thread reads the chunks it staged itself)
    {
      const int row = t >> 3;
      const int kc  = t & 7;
      float4 v0 = *(const float4*)&Af32[cur][t * 4];
      float4 v1 = *(const float4*)&Af32[cur][t * 4 + 1024];
      ushort4 p0, p1;
      p0.x = f2b(v0.x); p0.y = f2b(v0.y); p0.z = f2b(v0.z); p0.w = f2b(v0.w);
      p1.x = f2b(v1.x); p1.y = f2b(v1.y); p1.z = f2b(v1.z); p1.w = f2b(v1.w);
      *(ushort4*)&As[row * 32 + kc * 4]        = p0;
      *(ushort4*)&As[(row + 32) * 32 + kc * 4] = p1;
    }
    asm volatile("s_waitcnt lgkmcnt(0)\n\ts_barrier" ::: "memory");  // barrier A
    __builtin_amdgcn_sched_barrier(0);

    bf16x8 af[4], bfr[4];
#pragma unroll
    for (int i = 0; i < 4; ++i) af[i]  = *(const bf16x8*)&As[(i * 16 + r16) * 32 + q * 8];
#pragma unroll
    for (int j = 0; j < 4; ++j) bfr[j] = *(const bf16x8*)&Bs[cur][(wn + j * 16 + r16) * 32 + q * 8];
    asm volatile("s_waitcnt lgkmcnt(0)\n\ts_barrier" ::: "memory");  // barrier B
    __builtin_amdgcn_sched_barrier(0);

    if (it + 2 < nt) stage(it + 2, cur);

#pragma unroll
    for (int i = 0; i < 4; ++i)
#pragma unroll
      for (int j = 0; j < 4; ++j)
        acc[i][j] = __builtin_amdgcn_mfma_f32_16x16x32_bf16(af[i], bfr[j], acc[i][j], 0, 0, 0);
  }

#pragma unroll
  for (int i = 0; i < 4; ++i) {
#pragma unroll
    for (int r = 0; r < 4; ++r) {
      int m = m0 + i * 16 + q * 4 + r;
#pragma unroll
      for (int j = 0; j < 4; ++j) {
        int n = wn + j * 16 + r16;
        C[(size_t)m * 256 + n] = f2b(acc[i][j][r]);
      }
    }
  }
}

// ---------- K projection + HT emit: 128 m x 256 n, BK=64 merged (2 halves/barrier-pair) ----------
// R9-verified (409.9 us total). Same traffic as R4, half the barrier iterations.
// per half h: B-stage 2x gload_lds, A reg-staged 2x float4 (arow=t>>2, aseg=t&3),
// As[h] b128 write, At2[h] 8x b16 transposed write, At2 readback 4x b32, HT short8.
// vmem/stage = 8 (h0:B,B,A,A; h1:B,B,A,A); +2 HT stores/iter issued AFTER stage(m+2)
// (sched_barrier pinned). vmcnt audit: m0:8, m1:10, steady:12 (HT(m-2)2 +
// stage(m+1)8 + HT(m-1)2), last:4.  LDS 96.25 KB static.
DEV void projk2_step(int m, int nm, float4 (&VA)[2][2],
                     unsigned short* __restrict__ BsBuf,   // [2][256*32] halves
                     unsigned short* __restrict__ As,      // [2][128*32]
                     unsigned short* __restrict__ At2,     // [2][32*130]
                     const unsigned short* __restrict__ Bt,
                     unsigned short* __restrict__ HT,
                     const float* __restrict__ ag,
                     int K, int t, int wm, int wn, int r16, int q,
                     int arow, int aseg, int d, int lc,
                     size_t ht_base, floatx4 (&acc)[4][4]) {
  const int kt = m << 6;
  if (m == 0)            asm volatile("s_waitcnt vmcnt(8)"  ::: "memory");
  else if (m == 1)       asm volatile("s_waitcnt vmcnt(10)" ::: "memory");
  else if (m == nm - 1)  asm volatile("s_waitcnt vmcnt(4)"  ::: "memory");
  else                   asm volatile("s_waitcnt vmcnt(12)" ::: "memory");
  __builtin_amdgcn_sched_barrier(0);

  // ---- convert both halves: A regs -> As[h] (b128) + At2[h] transposed (8x b16) ----
#pragma unroll
  for (int h = 0; h < 2; ++h) {
    unsigned short e0 = f2b(VA[h][0].x), e1 = f2b(VA[h][0].y),
                   e2 = f2b(VA[h][0].z), e3 = f2b(VA[h][0].w);
    unsigned short e4 = f2b(VA[h][1].x), e5 = f2b(VA[h][1].y),
                   e6 = f2b(VA[h][1].z), e7 = f2b(VA[h][1].w);
    short8 pk;
    pk[0] = (short)e0; pk[1] = (short)e1; pk[2] = (short)e2; pk[3] = (short)e3;
    pk[4] = (short)e4; pk[5] = (short)e5; pk[6] = (short)e6; pk[7] = (short)e7;
    *(short8*)&As[h * 4096 + arow * 32 + aseg * 8] = pk;
    unsigned short* a2 = At2 + h * 4160;
    const int kb = aseg * 8;
    a2[(kb + 0) * 130 + arow] = e0;
    a2[(kb + 1) * 130 + arow] = e1;
    a2[(kb + 2) * 130 + arow] = e2;
    a2[(kb + 3) * 130 + arow] = e3;
    a2[(kb + 4) * 130 + arow] = e4;
    a2[(kb + 5) * 130 + arow] = e5;
    a2[(kb + 6) * 130 + arow] = e6;
    a2[(kb + 7) * 130 + arow] = e7;
  }
  asm volatile("s_waitcnt lgkmcnt(0)\n\ts_barrier" ::: "memory");  // barrier A
  __builtin_amdgcn_sched_barrier(0);

  // ---- frag phase: LDS reads only ----
  bf16x8 af[2][4], bfr[2][4];
#pragma unroll
  for (int h = 0; h < 2; ++h) {
#pragma unroll
    for (int i = 0; i < 4; ++i)
      af[h][i]  = *(const bf16x8*)&As[h * 4096 + (wm + i * 16 + r16) * 32 + q * 8];
#pragma unroll
    for (int j = 0; j < 4; ++j)
      bfr[h][j] = *(const bf16x8*)&BsBuf[h * 8192 + (wn + j * 16 + r16) * 32 + q * 8];
  }
  union { unsigned u[4]; short8 s; } vv0, vv1;
  {
    const unsigned* w0 = (const unsigned*)(At2)        + d * 65 + lc * 4;
    const unsigned* w1 = (const unsigned*)(At2 + 4160) + d * 65 + lc * 4;
    vv0.u[0] = w0[0]; vv0.u[1] = w0[1]; vv0.u[2] = w0[2]; vv0.u[3] = w0[3];
    vv1.u[0] = w1[0]; vv1.u[1] = w1[1]; vv1.u[2] = w1[2]; vv1.u[3] = w1[3];
  }
  asm volatile("s_waitcnt lgkmcnt(0)\n\ts_barrier" ::: "memory");  // barrier B
  __builtin_amdgcn_sched_barrier(0);

  // ---- post: stage(m+2) [8 vmem] ... pinned ... MFMA x32 + 2 HT stores ----
  if (m + 2 < nm) {
    const int kt2 = (m + 2) << 6;
#pragma unroll
    for (int h = 0; h < 2; ++h) {
#pragma unroll
      for (int cc = 0; cc < 2; ++cc) {
        int c = t + cc * 512;
        gload_lds16(Bt + (size_t)(c >> 2) * K + kt2 + h * 32 + (c & 3) * 8,
                    &BsBuf[h * 8192 + c * 8]);
      }
      VA[h][0] = *(const float4*)(ag + kt2 + h * 32);
      VA[h][1] = *(const float4*)(ag + kt2 + h * 32 + 4);
    }
  }
  __builtin_amdgcn_sched_barrier(0);  // pin: stage loads precede MFMA + HT stores

#pragma unroll
  for (int h = 0; h < 2; ++h)
#pragma unroll
    for (int i = 0; i < 4; ++i)
#pragma unroll
      for (int j = 0; j < 4; ++j)
        acc[i][j] = __builtin_amdgcn_mfma_f32_16x16x32_bf16(af[h][i], bfr[h][j], acc[i][j], 0, 0, 0);

  *(short8*)&HT[ht_base + (size_t)(kt)      * 2048] = vv0.s;
  *(short8*)&HT[ht_base + (size_t)(kt + 32) * 2048] = vv1.s;
}

__global__ __launch_bounds__(512) void proj_k(
    const float* __restrict__ A32, const unsigned short* __restrict__ Bt,
    unsigned short* __restrict__ C, unsigned short* __restrict__ HT,
    int K, int lda) {
  __shared__ unsigned short Bs[2][2][256 * 32];   // 64 KB (dbuf x 2 halves)
  __shared__ unsigned short As[2][128 * 32];      // 16 KB (2 halves)
  __shared__ unsigned short At2[2][32 * 130];     // 16.25 KB (2 halves)

  const int m0   = blockIdx.x * 128;
  const int t    = threadIdx.x;
  const int lane = t & 63;
  const int wave = t >> 6;            // 0..7
  const int wm   = (wave & 1) * 64;
  const int wn   = (wave >> 1) * 64;
  const int r16  = lane & 15;
  const int q    = lane >> 4;
  const int nm   = K >> 6;            // 20 (even)

  const int arow = t >> 2;            // 0..127
  const int aseg = t & 3;             // 0..3 (8 k each)
  const float* ag = A32 + (size_t)(m0 + arow) * lda + aseg * 8;

  const int d  = t >> 4;              // 0..31 (HT k-row within half)
  const int lc = t & 15;
  const size_t ht_base = ((size_t)(m0 >> 11) * 1280 + d) * 2048 + (m0 & 2047) + lc * 8;

  floatx4 acc[4][4];
#pragma unroll
  for (int i = 0; i < 4; ++i)
#pragma unroll
    for (int j = 0; j < 4; ++j) acc[i][j] = (floatx4){0.f, 0.f, 0.f, 0.f};

  float4 vaA[2][2], vaB[2][2];
  // prologue: stage(0)->Bs[0]+vaA, stage(1)->Bs[1]+vaB (order per half: B,B then A,A)
#pragma unroll
  for (int h = 0; h < 2; ++h) {
#pragma unroll
    for (int cc = 0; cc < 2; ++cc) {
      int c = t + cc * 512;
      gload_lds16(Bt + (size_t)(c >> 2) * K + h * 32 + (c & 3) * 8, &Bs[0][h][c * 8]);
    }
    vaA[h][0] = *(const float4*)(ag + h * 32);
    vaA[h][1] = *(const float4*)(ag + h * 32 + 4);
  }
#pragma unroll
  for (int h = 0; h < 2; ++h) {
#pragma unroll
    for (int cc = 0; cc < 2; ++cc) {
      int c = t + cc * 512;
      gload_lds16(Bt + (size_t)(c >> 2) * K + 64 + h * 32 + (c & 3) * 8, &Bs[1][h][c * 8]);
    }
    vaB[h][0] = *(const float4*)(ag + 64 + h * 32);
    vaB[h][1] = *(const float4*)(ag + 64 + h * 32 + 4);
  }

  for (int m2 = 0; m2 < nm; m2 += 2) {
    projk2_step(m2,     nm, vaA, &Bs[0][0][0], &As[0][0], &At2[0][0], Bt, HT, ag, K,
                t, wm, wn, r16, q, arow, aseg, d, lc, ht_base, acc);
    projk2_step(m2 + 1, nm, vaB, &Bs[1][0][0], &As[0][0], &At2[0][0], Bt, HT, ag, K,
                t, wm, wn, r16, q, arow, aseg, d, lc, ht_base, acc);
  }

  // epilogue: bf16 store, ldc = 256
#pragma unroll
  for (int i = 0; i < 4; ++i) {
#pragma unroll
    for (int r = 0; r < 4; ++r) {
      int m = m0 + wm + i * 16 + q * 4 + r;
#pragma unroll
      for (int j = 0; j < 4; ++j) {
        int n = wn + j * 16 + r16;
        C[(size_t)m * 256 + n] = f2b(acc[i][j][r]);
      }
    }
  }
}

// ---------- NT GEMM, 128x128 tile, XCD-swizzled 1D grid (R7-verified, unchanged) ----------
// Single-__syncthreads-per-iteration double-buffer:
//   stage(0); sync;
//   loop: { stage(it+1) -> buf^1; frag-read buf[cur]; MFMA; sync; }
// EPI 1: C=bf16 exp(v*escale), atomicAdd row sums.  EPI 2: C=f32 v/sums[row].
template <int EPI>
__global__ void gemm_nt(const unsigned short* __restrict__ Ab, const unsigned short* __restrict__ Btb,
                        void* __restrict__ Cpv, float* __restrict__ sums,
                        int K, int lda, int ldb, int ldc,
                        long long sA, long long sB, long long sC, int sstride,
                        float escale, int nx, int tiles_pb) {
  __shared__ unsigned short As[2][128 * 32];   // 16 KB (dbuf)
  __shared__ unsigned short Bs[2][128 * 32];   // 16 KB (dbuf)

  const int g   = blockIdx.x;
  const int xcd = g & 7;
  const int jj  = g >> 3;
  const int bz  = xcd * 2 + jj / tiles_pb;
  const int tt  = jj % tiles_pb;
  const int m0  = (tt / nx) * 128;
  const int n0  = (tt % nx) * 128;

  const int t    = threadIdx.x;
  const int lane = t & 63;
  const int wave = t >> 6;
  const int wm   = (wave & 1) * 64;
  const int wn   = (wave >> 1) * 64;
  const int r16  = lane & 15;
  const int q    = lane >> 4;
  const int nt   = K >> 5;

  const unsigned short* Bt = Btb + (long long)bz * sB;
  const unsigned short* A  = Ab + (long long)bz * sA;

  floatx4 acc[4][4];
#pragma unroll
  for (int i = 0; i < 4; ++i)
#pragma unroll
    for (int j = 0; j < 4; ++j) acc[i][j] = (floatx4){0.f, 0.f, 0.f, 0.f};

  // stage(it) -> buf: B (2 chunks) then A (2 chunks); 4 vmem ops.
  auto stage = [&](int it, int buf) {
    const int kt = it << 5;
#pragma unroll
    for (int cc = 0; cc < 2; ++cc) {
      int c = t + cc * 256;
      gload_lds16(Bt + (size_t)(n0 + (c >> 2)) * ldb + kt + (c & 3) * 8, &Bs[buf][c * 8]);
    }
#pragma unroll
    for (int cc = 0; cc < 2; ++cc) {
      int c = t + cc * 256;
      gload_lds16(A + (size_t)(m0 + (c >> 2)) * lda + kt + (c & 3) * 8, &As[buf][c * 8]);
    }
  };

  stage(0, 0);
  __syncthreads();   // stage(0) landed and visible

  for (int it = 0; it < nt; ++it) {
    const int cur = it & 1;

    if (it + 1 < nt) stage(it + 1, cur ^ 1);   // prefetch next tile into other buffer

    bf16x8 af[4], bfr[4];
#pragma unroll
    for (int i = 0; i < 4; ++i) af[i]  = *(const bf16x8*)&As[cur][(wm + i * 16 + r16) * 32 + q * 8];
#pragma unroll
    for (int j = 0; j < 4; ++j) bfr[j] = *(const bf16x8*)&Bs[cur][(wn + j * 16 + r16) * 32 + q * 8];
#pragma unroll
    for (int i = 0; i < 4; ++i)
#pragma unroll
      for (int j = 0; j < 4; ++j)
        acc[i][j] = __builtin_amdgcn_mfma_f32_16x16x32_bf16(af[i], bfr[j], acc[i][j], 0, 0, 0);

    __syncthreads();   // drains prefetch (hidden under frag+MFMA); protects buffer reuse
  }

  if constexpr (EPI == 1) {
    unsigned short* C = (unsigned short*)Cpv + (long long)bz * sC;
#pragma unroll
    for (int i = 0; i < 4; ++i) {
#pragma unroll
      for (int r = 0; r < 4; ++r) {
        int m = m0 + wm + i * 16 + q * 4 + r;
        float ps = 0.f;
#pragma unroll
        for (int j = 0; j < 4; ++j) {
          int n = n0 + wn + j * 16 + r16;
          float v = __expf(acc[i][j][r] * escale);
          ps += v;
          C[(size_t)m * ldc + n] = f2b(v);
        }
        // reduce over the 16 lanes sharing this row
#pragma unroll
        for (int msk = 1; msk < 16; msk <<= 1) ps += __shfl_xor(ps, msk, 64);
        if (r16 == 0) atomicAdd(&sums[(long long)bz * sstride + m], ps);
      }
    }
  } else {
    float* C = (float*)Cpv + (long long)bz * sC;
    const float* sb = sums + (long long)bz * sstride;
#pragma unroll
    for (int i = 0; i < 4; ++i) {
#pragma unroll
      for (int r = 0; r < 4; ++r) {
        int m = m0 + wm + i * 16 + q * 4 + r;
        float sc = 1.0f / sb[m];
#pragma unroll
        for (int j = 0; j < 4; ++j) {
          int n = n0 + wn + j * 16 + r16;
          C[(size_t)m * ldc + n] = acc[i][j][r] * sc;
        }
      }
    }
  }
}

// ---------- launch ----------
extern "C" void kernel_launch(void* const* d_in, const int* in_sizes, int n_in,
                              void* d_out, int out_size, void* d_ws, size_t ws_size,
                              hipStream_t stream) {
  (void)in_sizes; (void)n_in; (void)out_size; (void)ws_size;
  const float* H  = (const float*)d_in[0];   // [16][2048][1280]
  const float* G  = (const float*)d_in[1];   // [16][512][768]
  const float* Wq = (const float*)d_in[2];   // [256][768]
  const float* Wk = (const float*)d_in[3];   // [256][1280]
  float* Z = (float*)d_out;                  // [16][512][1280]

  constexpr int B = 16, L = 2048, Dh = 1280, T = 512, Dg = 768, P = 256;

  char* ws = (char*)d_ws;
  size_t off = 0;
  auto alloc = [&](size_t bytes) { void* p = ws + off; off += (bytes + 255) & ~(size_t)255; return p; };
  unsigned short* Wqbf = (unsigned short*)alloc((size_t)P * Dg * 2);
  unsigned short* Wkbf = (unsigned short*)alloc((size_t)P * Dh * 2);
  unsigned short* Qbf  = (unsigned short*)alloc((size_t)B * T * P * 2);    // 4 MB
  unsigned short* Kbf  = (unsigned short*)alloc((size_t)B * L * P * 2);    // 16 MB
  unsigned short* HT   = (unsigned short*)alloc((size_t)B * Dh * L * 2);   // 80 MB
  unsigned short* E    = (unsigned short*)alloc((size_t)B * T * L * 2);    // 32 MB
  float*          sums = (float*)alloc((size_t)B * T * 4);
  // total ~132 MB of ws

  // weights convert + sums zero-init (one small kernel)
  {
    int na4 = P * Dg / 4, nb4 = P * Dh / 4, nz = B * T;
    cvtw_kernel<<<(na4 + nb4 + nz + 255) / 256, 256, 0, stream>>>(
        Wq, Wqbf, na4, Wk, Wkbf, nb4, sums, nz);
  }

  // Q = G(f32) * Wqbf^T : [8192][256], G fetched once
  proj_gemm<0><<<B * T / 64, 256, 0, stream>>>(G, Wqbf, Qbf, nullptr, Dg, Dg);
  // K = H(f32) * Wkbf^T : [32768][256] + HT emit, BK=64 merged, grid 256
  proj_k<<<B * L / 128, 512, 0, stream>>>(H, Wkbf, Kbf, HT, Dh, Dh);

  // E = exp(scale * Qb * Kb^T) + row sums : per b [512][2048], 64 tiles/batch
  gemm_nt<1><<<B * (T / 128) * (L / 128), 256, 0, stream>>>(
      Qbf, Kbf, E, sums, P, P, P, L,
      (long long)T * P, (long long)L * P, (long long)T * L, T,
      0.0625f, L / 128, (T / 128) * (L / 128));

  // Z = diag(1/sums) * Eb * HTb^T : per b [512][1280] f32, 40 tiles/batch
  gemm_nt<2><<<B * (T / 128) * (Dh / 128), 256, 0, stream>>>(
      E, HT, Z, sums, L, L, L, Dh,
      (long long)T * L, (long long)Dh * L, (long long)T * Dh, T,
      0.f, Dh / 128, (T / 128) * (Dh / 128));
}